// Round 3
// baseline (647.686 us; speedup 1.0000x reference)
//
#include <hip/hip_runtime.h>
#include <hip/hip_bf16.h>

// GCNConv: out = D^-1/2 (A) D^-1/2 (X @ W) + bias,  deg = rowsum(A) + l
// N=8192, DIN=DOUT=256. A fp32 [N][N], X fp32 [N][256], W fp32 [256][256].
//
// Refactor: out[i,:] = d_i * sum_j A[i,j] * (d_j * S[j,:]),  S = X@W.
// Pipeline:
//   k1: d[i] = rsqrt(rowsum(A_i) + l)            (256 MB pass)
//   k2: W_T[n][i] = bf16(W[i][n])                (B-operand K-contiguous)
//   k3: S_T[n][j] = bf16(d_j * (X@W)[j][n])      (MFMA, transposed store)
//   k4: out += d_i * (A @ S_T^T), bias on k-chunk 0   (MFMA, fp32 atomics)
//
// R2 -> R3: main_gemm was latency-bound (21% HBM, 20.6% occupancy, grid=512
// blocks = 2/CU). Tile M 64->32, k-chunks 4->8: grid 2048 = 8 blocks/CU.

typedef __attribute__((ext_vector_type(8))) short short8;
typedef __attribute__((ext_vector_type(4))) float f32x4;

#define NN 8192
#define DD 256

// fp32 -> bf16 RNE (no NaN guard: inputs are finite)
__device__ inline unsigned short f2bfu(float x) {
    unsigned int u = __builtin_bit_cast(unsigned int, x);
    u += 0x7fffu + ((u >> 16) & 1u);
    return (unsigned short)(u >> 16);
}
__device__ inline unsigned int f2bf2u(float x, float y) {
    return (unsigned int)f2bfu(x) | ((unsigned int)f2bfu(y) << 16);
}
// 8 fp32 -> short8 holding 8 bf16 (RNE), k-order preserved
__device__ inline short8 cvt8(float4 a, float4 b) {
    union { unsigned int i[4]; short8 s; } u;
    u.i[0] = f2bf2u(a.x, a.y);
    u.i[1] = f2bf2u(a.z, a.w);
    u.i[2] = f2bf2u(b.x, b.y);
    u.i[3] = f2bf2u(b.z, b.w);
    return u.s;
}

// ---------------- k1: row sums -> d[i] -----------------------------------
__global__ __launch_bounds__(256) void rowsum_kernel(const float* __restrict__ A,
                                                     const int* __restrict__ lp,
                                                     float* __restrict__ d) {
    const int row = blockIdx.x;
    const int t = threadIdx.x;
    const float4* Arow = (const float4*)(A + (size_t)row * NN);
    float s = 0.f;
#pragma unroll
    for (int it = 0; it < NN / 4 / 256; ++it) {
        float4 v = Arow[it * 256 + t];
        s += (v.x + v.y) + (v.z + v.w);
    }
#pragma unroll
    for (int off = 32; off > 0; off >>= 1) s += __shfl_down(s, off, 64);
    __shared__ float wsum[4];
    if ((t & 63) == 0) wsum[t >> 6] = s;
    __syncthreads();
    if (t == 0) {
        float deg = ((wsum[0] + wsum[1]) + (wsum[2] + wsum[3])) + (float)(*lp);
        d[row] = deg > 0.f ? rsqrtf(deg) : 0.f;
    }
}

// ---------------- k2: W^T -> bf16 ----------------------------------------
__global__ __launch_bounds__(256) void wtrans_kernel(const float* __restrict__ W,
                                                     unsigned short* __restrict__ WT) {
    __shared__ unsigned short tile[64][65];
    const int tx = threadIdx.x & 63, ty = threadIdx.x >> 6;
    const int i0 = (blockIdx.x & 3) * 64;
    const int n0 = (blockIdx.x >> 2) * 64;
#pragma unroll
    for (int r = ty; r < 64; r += 4)
        tile[r][tx] = f2bfu(W[(size_t)(i0 + r) * DD + n0 + tx]);
    __syncthreads();
#pragma unroll
    for (int r = ty; r < 64; r += 4)
        WT[(size_t)(n0 + r) * DD + i0 + tx] = tile[tx][r];
}

// ---------------- k3: S_T[n][j] = bf16(d_j * (X@W)[j][n]) ----------------
__global__ __launch_bounds__(256) void support_kernel(const float* __restrict__ X,
                                                      const unsigned short* __restrict__ WT,
                                                      const float* __restrict__ d,
                                                      unsigned short* __restrict__ ST) {
    const int j0 = blockIdx.x * 64;
    const int lane = threadIdx.x & 63;
    const int w = threadIdx.x >> 6;
    const int q = lane >> 4;
    const int l15 = lane & 15;
    const int nb = w * 64;

    f32x4 acc[4][4];
#pragma unroll
    for (int a = 0; a < 4; ++a)
#pragma unroll
        for (int b = 0; b < 4; ++b) acc[a][b] = (f32x4)(0.f);

    const float* Xbase = X + (size_t)(j0 + l15) * DD + q * 8;
    const unsigned short* Wbase = WT + (size_t)(nb + l15) * DD + q * 8;

#pragma unroll
    for (int k0 = 0; k0 < DD; k0 += 32) {
        short8 afr[4], bfr[4];
#pragma unroll
        for (int mi = 0; mi < 4; ++mi) {
            const float4* p = (const float4*)(Xbase + mi * 16 * DD + k0);
            afr[mi] = cvt8(p[0], p[1]);
        }
#pragma unroll
        for (int ni = 0; ni < 4; ++ni)
            bfr[ni] = *(const short8*)(Wbase + ni * 16 * DD + k0);
#pragma unroll
        for (int mi = 0; mi < 4; ++mi)
#pragma unroll
            for (int ni = 0; ni < 4; ++ni)
                acc[mi][ni] = __builtin_amdgcn_mfma_f32_16x16x32_bf16(afr[mi], bfr[ni], acc[mi][ni], 0, 0, 0);
    }

    // C/D: col = lane&15 (n), row = q*4 + reg (j). Store 4 consecutive j as 8B.
#pragma unroll
    for (int mi = 0; mi < 4; ++mi) {
        const int j0r = j0 + mi * 16 + q * 4;
        float dj[4];
#pragma unroll
        for (int r = 0; r < 4; ++r) dj[r] = d[j0r + r];
#pragma unroll
        for (int ni = 0; ni < 4; ++ni) {
            const int n = nb + ni * 16 + l15;
            unsigned int lo = f2bf2u(acc[mi][ni][0] * dj[0], acc[mi][ni][1] * dj[1]);
            unsigned int hi = f2bf2u(acc[mi][ni][2] * dj[2], acc[mi][ni][3] * dj[3]);
            *(uint2*)(ST + (size_t)n * NN + j0r) = make_uint2(lo, hi);
        }
    }
}

// ---------------- k4: main GEMM out += d_i * (A @ S_T^T) (+bias) ---------
// grid = 256 m-tiles x 8 k-chunks (mt fastest -> same-kc blocks share ST
// slice in XCD L2). Block tile: M=32, N=256 (wave w: n in [64w, 64w+64)).
#define KCHUNK 1024
#define NMT (NN / 32)
__global__ __launch_bounds__(256) void main_gemm(const float* __restrict__ A,
                                                 const unsigned short* __restrict__ ST,
                                                 const float* __restrict__ d,
                                                 const float* __restrict__ bias,
                                                 float* __restrict__ out) {
    const int mt = blockIdx.x & (NMT - 1);
    const int kc = blockIdx.x / NMT;
    const int m0 = mt * 32;
    const int kbeg = kc * KCHUNK;
    const int lane = threadIdx.x & 63;
    const int w = threadIdx.x >> 6;
    const int q = lane >> 4;
    const int l15 = lane & 15;
    const int nb = w * 64;

    f32x4 acc[2][4];
#pragma unroll
    for (int a = 0; a < 2; ++a)
#pragma unroll
        for (int b = 0; b < 4; ++b) acc[a][b] = (f32x4)(0.f);

    const float* Abase = A + (size_t)(m0 + l15) * NN + q * 8;
    const unsigned short* Bbase = ST + (size_t)(nb + l15) * NN + q * 8;

    for (int k0 = kbeg; k0 < kbeg + KCHUNK; k0 += 32) {
        short8 afr[2], bfr[4];
#pragma unroll
        for (int mi = 0; mi < 2; ++mi) {
            const float4* p = (const float4*)(Abase + (size_t)mi * 16 * NN + k0);
            float4 v0 = p[0];
            float4 v1 = p[1];
            afr[mi] = cvt8(v0, v1);
        }
#pragma unroll
        for (int ni = 0; ni < 4; ++ni)
            bfr[ni] = *(const short8*)(Bbase + (size_t)ni * 16 * NN + k0);
#pragma unroll
        for (int mi = 0; mi < 2; ++mi)
#pragma unroll
            for (int ni = 0; ni < 4; ++ni)
                acc[mi][ni] = __builtin_amdgcn_mfma_f32_16x16x32_bf16(afr[mi], bfr[ni], acc[mi][ni], 0, 0, 0);
    }

    // epilogue: out[m][n] += d[m]*acc (+ bias once, from k-chunk 0)
#pragma unroll
    for (int mi = 0; mi < 2; ++mi) {
        const int r0 = m0 + mi * 16 + q * 4;
        float dm[4];
#pragma unroll
        for (int r = 0; r < 4; ++r) dm[r] = d[r0 + r];
#pragma unroll
        for (int ni = 0; ni < 4; ++ni) {
            const int n = nb + ni * 16 + l15;
            const float bv = (kc == 0) ? bias[n] : 0.f;
#pragma unroll
            for (int r = 0; r < 4; ++r) {
                float val = acc[mi][ni][r] * dm[r] + bv;
                unsafeAtomicAdd(out + (size_t)(r0 + r) * DD + n, val);
            }
        }
    }
}

extern "C" void kernel_launch(void* const* d_in, const int* in_sizes, int n_in,
                              void* d_out, int out_size, void* d_ws, size_t ws_size,
                              hipStream_t stream) {
    const float* A = (const float*)d_in[0];
    const float* X = (const float*)d_in[1];
    const float* W = (const float*)d_in[2];
    const float* bias = (const float*)d_in[3];
    const int* lp = (const int*)d_in[4];
    float* out = (float*)d_out;

    // workspace layout: d[8192] f32 | W_T bf16[256*256] | S_T bf16[256*8192]
    float* d = (float*)d_ws;
    unsigned short* WT = (unsigned short*)((char*)d_ws + 32768);
    unsigned short* ST = (unsigned short*)((char*)d_ws + 32768 + 131072);

    (void)hipMemsetAsync(d_out, 0, (size_t)NN * DD * sizeof(float), stream);
    rowsum_kernel<<<NN, 256, 0, stream>>>(A, lp, d);
    wtrans_kernel<<<16, 256, 0, stream>>>(W, WT);
    support_kernel<<<NN / 64, 256, 0, stream>>>(X, WT, d, ST);
    main_gemm<<<NMT * (NN / KCHUNK), 256, 0, stream>>>(A, ST, d, bias, out);
}

// Round 4
// 511.599 us; speedup vs baseline: 1.2660x; 1.2660x over previous
//
#include <hip/hip_runtime.h>
#include <hip/hip_bf16.h>

// GCNConv: out = D^-1/2 (A) D^-1/2 (X @ W) + bias,  deg = rowsum(A) + l
// N=8192, DIN=DOUT=256. A fp32 [N][N], X fp32 [N][256], W fp32 [256][256].
//
// Refactor: out[i,:] = d_i * sum_j A[i,j] * (d_j * S[j,:]),  S = X@W.
//   k1: d[i] = rsqrt(rowsum(A_i) + l)
//   k2: W_T[n][i] = bf16(W[i][n])
//   k3: S_T[n][j] = bf16(d_j * (X@W)[j][n])
//   k4: out += d_i * (A @ S_T^T), bias on k-chunk 0
//
// R3 -> R4: k4 was latency-serialized (L3-warm replays still 255 us; ~96 B
// in flight per wave). Rebuilt as double-buffered LDS GEMM: 16 KB A-tile
// staged per BK=64 iter (fp32 global -> VGPR -> bf16 LDS), loads issued a
// full compute-phase ahead. M=64, kc=8, grid 1024. support_kernel 128->512
// blocks (was leaving half the CUs idle).

typedef __attribute__((ext_vector_type(8))) short short8;
typedef __attribute__((ext_vector_type(4))) float f32x4;

#define NN 8192
#define DD 256

// fp32 -> bf16 RNE (no NaN guard: inputs are finite)
__device__ inline unsigned short f2bfu(float x) {
    unsigned int u = __builtin_bit_cast(unsigned int, x);
    u += 0x7fffu + ((u >> 16) & 1u);
    return (unsigned short)(u >> 16);
}
__device__ inline unsigned int f2bf2u(float x, float y) {
    return (unsigned int)f2bfu(x) | ((unsigned int)f2bfu(y) << 16);
}
__device__ inline short8 cvt8(float4 a, float4 b) {
    union { unsigned int i[4]; short8 s; } u;
    u.i[0] = f2bf2u(a.x, a.y);
    u.i[1] = f2bf2u(a.z, a.w);
    u.i[2] = f2bf2u(b.x, b.y);
    u.i[3] = f2bf2u(b.z, b.w);
    return u.s;
}

// ---------------- k1: row sums -> d[i] -----------------------------------
__global__ __launch_bounds__(256) void rowsum_kernel(const float* __restrict__ A,
                                                     const int* __restrict__ lp,
                                                     float* __restrict__ d) {
    const int row = blockIdx.x;
    const int t = threadIdx.x;
    const float4* Arow = (const float4*)(A + (size_t)row * NN);
    float s = 0.f;
#pragma unroll
    for (int it = 0; it < NN / 4 / 256; ++it) {
        float4 v = Arow[it * 256 + t];
        s += (v.x + v.y) + (v.z + v.w);
    }
#pragma unroll
    for (int off = 32; off > 0; off >>= 1) s += __shfl_down(s, off, 64);
    __shared__ float wsum[4];
    if ((t & 63) == 0) wsum[t >> 6] = s;
    __syncthreads();
    if (t == 0) {
        float deg = ((wsum[0] + wsum[1]) + (wsum[2] + wsum[3])) + (float)(*lp);
        d[row] = deg > 0.f ? rsqrtf(deg) : 0.f;
    }
}

// ---------------- k2: W^T -> bf16 ----------------------------------------
__global__ __launch_bounds__(256) void wtrans_kernel(const float* __restrict__ W,
                                                     unsigned short* __restrict__ WT) {
    __shared__ unsigned short tile[64][65];
    const int tx = threadIdx.x & 63, ty = threadIdx.x >> 6;
    const int i0 = (blockIdx.x & 3) * 64;
    const int n0 = (blockIdx.x >> 2) * 64;
#pragma unroll
    for (int r = ty; r < 64; r += 4)
        tile[r][tx] = f2bfu(W[(size_t)(i0 + r) * DD + n0 + tx]);
    __syncthreads();
#pragma unroll
    for (int r = ty; r < 64; r += 4)
        WT[(size_t)(n0 + r) * DD + i0 + tx] = tile[tx][r];
}

// ---------------- k3: S_T[n][j] = bf16(d_j * (X@W)[j][n]) ----------------
// j-tile = 16 -> 512 blocks (2/CU); wave w covers n in [64w, 64w+64).
__global__ __launch_bounds__(256) void support_kernel(const float* __restrict__ X,
                                                      const unsigned short* __restrict__ WT,
                                                      const float* __restrict__ d,
                                                      unsigned short* __restrict__ ST) {
    const int j0 = blockIdx.x * 16;
    const int lane = threadIdx.x & 63;
    const int w = threadIdx.x >> 6;
    const int q = lane >> 4;
    const int l15 = lane & 15;
    const int nb = w * 64;

    f32x4 acc[4];
#pragma unroll
    for (int b = 0; b < 4; ++b) acc[b] = (f32x4)(0.f);

    const float* Xbase = X + (size_t)(j0 + l15) * DD + q * 8;
    const unsigned short* Wbase = WT + (size_t)(nb + l15) * DD + q * 8;

#pragma unroll
    for (int k0 = 0; k0 < DD; k0 += 32) {
        const float4* p = (const float4*)(Xbase + k0);
        short8 afr = cvt8(p[0], p[1]);
        short8 bfr[4];
#pragma unroll
        for (int ni = 0; ni < 4; ++ni)
            bfr[ni] = *(const short8*)(Wbase + ni * 16 * DD + k0);
#pragma unroll
        for (int ni = 0; ni < 4; ++ni)
            acc[ni] = __builtin_amdgcn_mfma_f32_16x16x32_bf16(afr, bfr[ni], acc[ni], 0, 0, 0);
    }

    // C/D: col = lane&15 (n), row = q*4 + reg (j). Store 4 consecutive j as 8B.
    const int j0r = j0 + q * 4;
    float dj[4];
#pragma unroll
    for (int r = 0; r < 4; ++r) dj[r] = d[j0r + r];
#pragma unroll
    for (int ni = 0; ni < 4; ++ni) {
        const int n = nb + ni * 16 + l15;
        unsigned int lo = f2bf2u(acc[ni][0] * dj[0], acc[ni][1] * dj[1]);
        unsigned int hi = f2bf2u(acc[ni][2] * dj[2], acc[ni][3] * dj[3]);
        *(uint2*)(ST + (size_t)n * NN + j0r) = make_uint2(lo, hi);
    }
}

// ---------------- k4: main GEMM out += d_i * (A @ S_T^T) (+bias) ---------
// Double-buffered LDS staging of A (fp32 global -> VGPR -> bf16 LDS).
// Block tile M=64, N=256, BK=64. grid = 128 mt x 8 kc = 1024 blocks.
#define KCHUNK 1024
#define BK 64
#define NITER (KCHUNK / BK)
__global__ __launch_bounds__(256) void main_gemm(const float* __restrict__ A,
                                                 const unsigned short* __restrict__ ST,
                                                 const float* __restrict__ d,
                                                 const float* __restrict__ bias,
                                                 float* __restrict__ out) {
    // rows padded 64 -> 72 bf16: fragment ds_read_b128 lands 2-way on banks (free)
    __shared__ __align__(16) unsigned short Abuf[2][64][72];

    const int mt = blockIdx.x & 127;
    const int kc = blockIdx.x >> 7;
    const int m0 = mt * 64;
    const int kbeg = kc * KCHUNK;
    const int tid = threadIdx.x;
    const int lane = tid & 63;
    const int w = tid >> 6;
    const int q = lane >> 4;
    const int l15 = lane & 15;
    const int nb = w * 64;
    const int srow = tid >> 4;        // 0..15 (staging row within 16-row group)
    const int scol = (tid & 15) * 4;  // staging k-col (floats)

    const float* Ast = A + (size_t)(m0 + srow) * NN + kbeg + scol;
    const unsigned short* Bbase = ST + (size_t)(nb + l15) * NN + kbeg + q * 8;

    f32x4 acc[4][4];
#pragma unroll
    for (int a = 0; a < 4; ++a)
#pragma unroll
        for (int b = 0; b < 4; ++b) acc[a][b] = (f32x4)(0.f);

    float4 nx[4];
    // prologue: stage tile 0
#pragma unroll
    for (int p = 0; p < 4; ++p)
        nx[p] = *(const float4*)(Ast + (size_t)(p * 16) * NN);
#pragma unroll
    for (int p = 0; p < 4; ++p)
        *(uint2*)&Abuf[0][srow + p * 16][scol] =
            make_uint2(f2bf2u(nx[p].x, nx[p].y), f2bf2u(nx[p].z, nx[p].w));
    __syncthreads();

    for (int it = 0; it < NITER; ++it) {
        const int buf = it & 1;
        // issue next tile's global loads a full compute-phase ahead
        if (it + 1 < NITER) {
#pragma unroll
            for (int p = 0; p < 4; ++p)
                nx[p] = *(const float4*)(Ast + (size_t)(p * 16) * NN + (it + 1) * BK);
        }
#pragma unroll
        for (int kk = 0; kk < BK; kk += 32) {
            short8 afr[4], bfr[4];
#pragma unroll
            for (int mi = 0; mi < 4; ++mi)
                afr[mi] = *(const short8*)&Abuf[buf][mi * 16 + l15][kk + q * 8];
#pragma unroll
            for (int ni = 0; ni < 4; ++ni)
                bfr[ni] = *(const short8*)(Bbase + (size_t)(ni * 16) * NN + it * BK + kk);
#pragma unroll
            for (int mi = 0; mi < 4; ++mi)
#pragma unroll
                for (int ni = 0; ni < 4; ++ni)
                    acc[mi][ni] = __builtin_amdgcn_mfma_f32_16x16x32_bf16(afr[mi], bfr[ni], acc[mi][ni], 0, 0, 0);
        }
        if (it + 1 < NITER) {
            __syncthreads();  // all waves done reading buf^1 (tile it-1)
#pragma unroll
            for (int p = 0; p < 4; ++p)
                *(uint2*)&Abuf[buf ^ 1][srow + p * 16][scol] =
                    make_uint2(f2bf2u(nx[p].x, nx[p].y), f2bf2u(nx[p].z, nx[p].w));
            __syncthreads();  // writes visible before next compute
        }
    }

    // epilogue: out[m][n] += d[m]*acc (+ bias once, from k-chunk 0)
#pragma unroll
    for (int mi = 0; mi < 4; ++mi) {
        const int r0 = m0 + mi * 16 + q * 4;
        float dm[4];
#pragma unroll
        for (int r = 0; r < 4; ++r) dm[r] = d[r0 + r];
#pragma unroll
        for (int ni = 0; ni < 4; ++ni) {
            const int n = nb + ni * 16 + l15;
            const float bv = (kc == 0) ? bias[n] : 0.f;
#pragma unroll
            for (int r = 0; r < 4; ++r) {
                float val = acc[mi][ni][r] * dm[r] + bv;
                unsafeAtomicAdd(out + (size_t)(r0 + r) * DD + n, val);
            }
        }
    }
}

extern "C" void kernel_launch(void* const* d_in, const int* in_sizes, int n_in,
                              void* d_out, int out_size, void* d_ws, size_t ws_size,
                              hipStream_t stream) {
    const float* A = (const float*)d_in[0];
    const float* X = (const float*)d_in[1];
    const float* W = (const float*)d_in[2];
    const float* bias = (const float*)d_in[3];
    const int* lp = (const int*)d_in[4];
    float* out = (float*)d_out;

    // workspace layout: d[8192] f32 | W_T bf16[256*256] | S_T bf16[256*8192]
    float* d = (float*)d_ws;
    unsigned short* WT = (unsigned short*)((char*)d_ws + 32768);
    unsigned short* ST = (unsigned short*)((char*)d_ws + 32768 + 131072);

    (void)hipMemsetAsync(d_out, 0, (size_t)NN * DD * sizeof(float), stream);
    rowsum_kernel<<<NN, 256, 0, stream>>>(A, lp, d);
    wtrans_kernel<<<16, 256, 0, stream>>>(W, WT);
    support_kernel<<<NN / 16, 256, 0, stream>>>(X, WT, d, ST);
    main_gemm<<<128 * (NN / KCHUNK), 256, 0, stream>>>(A, ST, d, bias, out);
}

// Round 5
// 482.399 us; speedup vs baseline: 1.3426x; 1.0605x over previous
//
#include <hip/hip_runtime.h>
#include <hip/hip_bf16.h>

// GCNConv: out = D^-1/2 (A) D^-1/2 (X @ W) + bias,  deg = rowsum(A) + l
// N=8192, DIN=DOUT=256. A fp32 [N][N], X fp32 [N][256], W fp32 [256][256].
//
// Refactor: out[i,:] = d_i * sum_j A[i,j] * (d_j * S[j,:]),  S = X@W.
//   k1: d[i] = rsqrt(rowsum(A_i) + l)
//   k2: W_T[n][i] = bf16(W[i][n])
//   k3: S_T[n][j] = bf16(d_j * (X@W)[j][n])
//   k4: out += d_i * (A @ S_T^T), bias on k-chunk 0
//
// R4 -> R5: R4's prefetch was defeated by vmcnt ordering (B-frag waits in the
// compute phase retire the older A-prefetch loads; __syncthreads adds a
// vmcnt(0) drain). New k4: single raw s_barrier per BK iter (lgkmcnt only),
// A prefetched 2 phases deep in VGPRs, B frags prefetched 1 phase deep in
// registers -> every wait targets phase-old loads; vmcnt never drains the
// pipeline. kc 8->4 halves atomic traffic. A loads nontemporal (read-once).

typedef __attribute__((ext_vector_type(8))) short short8;
typedef __attribute__((ext_vector_type(4))) float f32x4;

#define NN 8192
#define DD 256

// fp32 -> bf16 RNE (no NaN guard: inputs are finite)
__device__ inline unsigned short f2bfu(float x) {
    unsigned int u = __builtin_bit_cast(unsigned int, x);
    u += 0x7fffu + ((u >> 16) & 1u);
    return (unsigned short)(u >> 16);
}
__device__ inline unsigned int f2bf2u(float x, float y) {
    return (unsigned int)f2bfu(x) | ((unsigned int)f2bfu(y) << 16);
}
__device__ inline short8 cvt8(float4 a, float4 b) {
    union { unsigned int i[4]; short8 s; } u;
    u.i[0] = f2bf2u(a.x, a.y);
    u.i[1] = f2bf2u(a.z, a.w);
    u.i[2] = f2bf2u(b.x, b.y);
    u.i[3] = f2bf2u(b.z, b.w);
    return u.s;
}

// ---------------- k1: row sums -> d[i] -----------------------------------
__global__ __launch_bounds__(256) void rowsum_kernel(const float* __restrict__ A,
                                                     const int* __restrict__ lp,
                                                     float* __restrict__ d) {
    const int row = blockIdx.x;
    const int t = threadIdx.x;
    const float4* Arow = (const float4*)(A + (size_t)row * NN);
    float s = 0.f;
#pragma unroll
    for (int it = 0; it < NN / 4 / 256; ++it) {
        float4 v = Arow[it * 256 + t];
        s += (v.x + v.y) + (v.z + v.w);
    }
#pragma unroll
    for (int off = 32; off > 0; off >>= 1) s += __shfl_down(s, off, 64);
    __shared__ float wsum[4];
    if ((t & 63) == 0) wsum[t >> 6] = s;
    __syncthreads();
    if (t == 0) {
        float deg = ((wsum[0] + wsum[1]) + (wsum[2] + wsum[3])) + (float)(*lp);
        d[row] = deg > 0.f ? rsqrtf(deg) : 0.f;
    }
}

// ---------------- k2: W^T -> bf16 ----------------------------------------
__global__ __launch_bounds__(256) void wtrans_kernel(const float* __restrict__ W,
                                                     unsigned short* __restrict__ WT) {
    __shared__ unsigned short tile[64][65];
    const int tx = threadIdx.x & 63, ty = threadIdx.x >> 6;
    const int i0 = (blockIdx.x & 3) * 64;
    const int n0 = (blockIdx.x >> 2) * 64;
#pragma unroll
    for (int r = ty; r < 64; r += 4)
        tile[r][tx] = f2bfu(W[(size_t)(i0 + r) * DD + n0 + tx]);
    __syncthreads();
#pragma unroll
    for (int r = ty; r < 64; r += 4)
        WT[(size_t)(n0 + r) * DD + i0 + tx] = tile[tx][r];
}

// ---------------- k3: S_T[n][j] = bf16(d_j * (X@W)[j][n]) ----------------
__global__ __launch_bounds__(256) void support_kernel(const float* __restrict__ X,
                                                      const unsigned short* __restrict__ WT,
                                                      const float* __restrict__ d,
                                                      unsigned short* __restrict__ ST) {
    const int j0 = blockIdx.x * 16;
    const int lane = threadIdx.x & 63;
    const int w = threadIdx.x >> 6;
    const int q = lane >> 4;
    const int l15 = lane & 15;
    const int nb = w * 64;

    f32x4 acc[4];
#pragma unroll
    for (int b = 0; b < 4; ++b) acc[b] = (f32x4)(0.f);

    const float* Xbase = X + (size_t)(j0 + l15) * DD + q * 8;
    const unsigned short* Wbase = WT + (size_t)(nb + l15) * DD + q * 8;

#pragma unroll
    for (int k0 = 0; k0 < DD; k0 += 32) {
        const float4* p = (const float4*)(Xbase + k0);
        short8 afr = cvt8(p[0], p[1]);
        short8 bfr[4];
#pragma unroll
        for (int ni = 0; ni < 4; ++ni)
            bfr[ni] = *(const short8*)(Wbase + ni * 16 * DD + k0);
#pragma unroll
        for (int ni = 0; ni < 4; ++ni)
            acc[ni] = __builtin_amdgcn_mfma_f32_16x16x32_bf16(afr, bfr[ni], acc[ni], 0, 0, 0);
    }

    const int j0r = j0 + q * 4;
    float dj[4];
#pragma unroll
    for (int r = 0; r < 4; ++r) dj[r] = d[j0r + r];
#pragma unroll
    for (int ni = 0; ni < 4; ++ni) {
        const int n = nb + ni * 16 + l15;
        unsigned int lo = f2bf2u(acc[ni][0] * dj[0], acc[ni][1] * dj[1]);
        unsigned int hi = f2bf2u(acc[ni][2] * dj[2], acc[ni][3] * dj[3]);
        *(uint2*)(ST + (size_t)n * NN + j0r) = make_uint2(lo, hi);
    }
}

// ---------------- k4: main GEMM out += d_i * (A @ S_T^T) (+bias) ---------
// Single-barrier pipelined GEMM. M=64, N=256, BK=64, KCHUNK=2048.
// grid = 128 mt x 4 kc = 512 blocks (2/CU). Per phase(it):
//   barrier(lgkm) | issue B(it+1)->regs | issue A(it+2)->regs |
//   LDS[(it+1)&1] <- cvt(A-regs tile it+1) | compute(it) from LDS[it&1]+B(it)
// All waits target phase-old loads: vmcnt never drains the pipeline.
#define KCHUNK 2048
#define BK 64
#define NITER (KCHUNK / BK)
__global__ __launch_bounds__(256) void main_gemm(const float* __restrict__ A,
                                                 const unsigned short* __restrict__ ST,
                                                 const float* __restrict__ d,
                                                 const float* __restrict__ bias,
                                                 float* __restrict__ out) {
    // rows padded 64 -> 72 bf16 (144 B): fragment ds_read_b128 2-way on banks (free)
    __shared__ __align__(16) unsigned short Abuf[2][64][72];

    const int mt = blockIdx.x & 127;
    const int kc = blockIdx.x >> 7;   // 0..3
    const int m0 = mt * 64;
    const int kbeg = kc * KCHUNK;
    const int tid = threadIdx.x;
    const int lane = tid & 63;
    const int w = tid >> 6;
    const int q = lane >> 4;
    const int l15 = lane & 15;
    const int nb = w * 64;
    const int srow = tid >> 4;        // 0..15
    const int scol = (tid & 15) * 4;  // k-col in floats

    const float* Ast = A + (size_t)(m0 + srow) * NN + kbeg + scol;
    const unsigned short* Bptr = ST + (size_t)(nb + l15) * NN + kbeg + q * 8;

    f32x4 acc[4][4];
#pragma unroll
    for (int a = 0; a < 4; ++a)
#pragma unroll
        for (int b = 0; b < 4; ++b) acc[a][b] = (f32x4)(0.f);

    f32x4 r[2][4];        // A pipeline, 2 phases deep
    short8 bfr[2][2][4];  // B frags [phase parity][kk2][ni], 1 phase deep

    // ---- prologue: issue A0->r[0], A1->r[1], B0->bfr[0]; LDS[0] <- tile0
#pragma unroll
    for (int p = 0; p < 4; ++p)
        r[0][p] = __builtin_nontemporal_load((const f32x4*)(Ast + (size_t)(p * 16) * NN));
#pragma unroll
    for (int p = 0; p < 4; ++p)
        r[1][p] = __builtin_nontemporal_load((const f32x4*)(Ast + (size_t)(p * 16) * NN + BK));
#pragma unroll
    for (int kk2 = 0; kk2 < 2; ++kk2)
#pragma unroll
        for (int ni = 0; ni < 4; ++ni)
            bfr[0][kk2][ni] = *(const short8*)(Bptr + (size_t)(ni * 16) * NN + kk2 * 32);
#pragma unroll
    for (int p = 0; p < 4; ++p) {
        f32x4 v = r[0][p];
        *(uint2*)&Abuf[0][srow + p * 16][scol] =
            make_uint2(f2bf2u(v[0], v[1]), f2bf2u(v[2], v[3]));
    }

#pragma unroll 2
    for (int it = 0; it < NITER; ++it) {
        const int buf = it & 1;
        // one barrier per phase; LDS-drain only, vmcnt left in flight
        __asm__ __volatile__("s_waitcnt lgkmcnt(0)\n\ts_barrier" ::: "memory");

        // prefetch B(it+1) (register-resident, used next phase)
        if (it + 1 < NITER) {
#pragma unroll
            for (int kk2 = 0; kk2 < 2; ++kk2)
#pragma unroll
                for (int ni = 0; ni < 4; ++ni)
                    bfr[buf ^ 1][kk2][ni] =
                        *(const short8*)(Bptr + (size_t)(ni * 16) * NN + (it + 1) * BK + kk2 * 32);
        }
        // issue A(it+2) into the reg set freed by tile it's LDS write
        if (it + 2 < NITER) {
#pragma unroll
            for (int p = 0; p < 4; ++p)
                r[buf][p] = __builtin_nontemporal_load(
                    (const f32x4*)(Ast + (size_t)(p * 16) * NN + (it + 2) * BK));
        }
        // stage tile it+1 into LDS (waits only its own phase-old loads)
        if (it + 1 < NITER) {
#pragma unroll
            for (int p = 0; p < 4; ++p) {
                f32x4 v = r[buf ^ 1][p];
                *(uint2*)&Abuf[buf ^ 1][srow + p * 16][scol] =
                    make_uint2(f2bf2u(v[0], v[1]), f2bf2u(v[2], v[3]));
            }
        }
        // compute tile it: pure LDS + register B -> no global waits
#pragma unroll
        for (int kk2 = 0; kk2 < 2; ++kk2) {
            short8 afr[4];
#pragma unroll
            for (int mi = 0; mi < 4; ++mi)
                afr[mi] = *(const short8*)&Abuf[buf][mi * 16 + l15][kk2 * 32 + q * 8];
#pragma unroll
            for (int mi = 0; mi < 4; ++mi)
#pragma unroll
                for (int ni = 0; ni < 4; ++ni)
                    acc[mi][ni] = __builtin_amdgcn_mfma_f32_16x16x32_bf16(
                        afr[mi], bfr[buf][kk2][ni], acc[mi][ni], 0, 0, 0);
        }
    }

    // epilogue: out[m][n] += d[m]*acc (+ bias once, from k-chunk 0)
#pragma unroll
    for (int mi = 0; mi < 4; ++mi) {
        const int r0 = m0 + mi * 16 + q * 4;
        float dm[4];
#pragma unroll
        for (int rr = 0; rr < 4; ++rr) dm[rr] = d[r0 + rr];
#pragma unroll
        for (int ni = 0; ni < 4; ++ni) {
            const int n = nb + ni * 16 + l15;
            const float bv = (kc == 0) ? bias[n] : 0.f;
#pragma unroll
            for (int rr = 0; rr < 4; ++rr) {
                float val = acc[mi][ni][rr] * dm[rr] + bv;
                unsafeAtomicAdd(out + (size_t)(r0 + rr) * DD + n, val);
            }
        }
    }
}

extern "C" void kernel_launch(void* const* d_in, const int* in_sizes, int n_in,
                              void* d_out, int out_size, void* d_ws, size_t ws_size,
                              hipStream_t stream) {
    const float* A = (const float*)d_in[0];
    const float* X = (const float*)d_in[1];
    const float* W = (const float*)d_in[2];
    const float* bias = (const float*)d_in[3];
    const int* lp = (const int*)d_in[4];
    float* out = (float*)d_out;

    // workspace layout: d[8192] f32 | W_T bf16[256*256] | S_T bf16[256*8192]
    float* d = (float*)d_ws;
    unsigned short* WT = (unsigned short*)((char*)d_ws + 32768);
    unsigned short* ST = (unsigned short*)((char*)d_ws + 32768 + 131072);

    (void)hipMemsetAsync(d_out, 0, (size_t)NN * DD * sizeof(float), stream);
    rowsum_kernel<<<NN, 256, 0, stream>>>(A, lp, d);
    wtrans_kernel<<<16, 256, 0, stream>>>(W, WT);
    support_kernel<<<NN / 16, 256, 0, stream>>>(X, WT, d, ST);
    main_gemm<<<128 * (NN / KCHUNK), 256, 0, stream>>>(A, ST, d, bias, out);
}